// Round 1
// baseline (734.945 us; speedup 1.0000x reference)
//
#include <hip/hip_runtime.h>

// EmbeddingLSQ: out[t,d] = (idx[t]==0) ? 0 : rint(clamp(W[d,idx[t]]/a,-8,7))*a
// idx[t] = position of the 1.0 in one-hot row x[t,:].
//
// v2: segment-parallel scan. The previous kernel's per-token windowed scan was
// a serial dependent chain (load 4KB -> drain -> ballot -> branch, ~16 round
// trips avg) and ran at ~0.5 TB/s effective. Here each row is split into 8
// segments of 4096 floats; grid = 8*4096 one-wave blocks in SEGMENT-MAJOR
// order. Each block issues all 16 v4f loads with no intra-scan dependency
// (full MLP, streaming BW), and the unique block whose segment contains the
// 1.0 performs the W-column gather + LSQ fake-quant + coalesced stores.
//
// Early-exit economy is recovered with a perf-HINT flag done[t] in d_ws
// (zeroed via hipMemsetAsync): the winner sets it device-scope; later-segment
// blocks skip if they see it. Stale reads are harmless (they scan zeros and
// exit), so correctness never depends on dispatch order or XCD coherence.

typedef float v4f __attribute__((ext_vector_type(4)));

constexpr int VOCAB   = 32000;
constexpr int DIM     = 1024;
constexpr int TOKENS  = 4096;
constexpr int WAVE    = 64;
constexpr int SEG_FLT = 4096;                              // floats per segment
constexpr int NSEG    = (VOCAB + SEG_FLT - 1) / SEG_FLT;   // 8 (last = 3328)
constexpr int FULL_ITERS = SEG_FLT / 4 / WAVE;             // 16 v4f per lane
constexpr int TAIL_FLT   = VOCAB - (NSEG - 1) * SEG_FLT;   // 3328
constexpr int TAIL_ITERS = TAIL_FLT / 4 / WAVE;            // 13 v4f per lane

__global__ __launch_bounds__(WAVE) void emb_lsq_seg(
    const float* __restrict__ x,
    const float* __restrict__ w,
    const float* __restrict__ alpha,
    float* __restrict__ out,
    int* __restrict__ done)
{
    const int bid  = blockIdx.x;
    const int seg  = bid >> 12;              // segment-major: all seg-0 blocks first
    const int t    = bid & (TOKENS - 1);
    const int lane = threadIdx.x;

    // Skip hint: an earlier segment's block already found this token's index.
    // Agent-scope load so we see the winner's flag across XCDs when possible;
    // a stale 0 merely costs a redundant scan of zeros.
    if (seg > 0 &&
        __hip_atomic_load(done + t, __ATOMIC_RELAXED, __HIP_MEMORY_SCOPE_AGENT) != 0)
        return;

    const int  base = seg * SEG_FLT;
    const v4f* xr   = reinterpret_cast<const v4f*>(x + (size_t)t * VOCAB + base);

    int found = -1;                          // global vocab column if found
    if (seg < NSEG - 1) {
        v4f v[FULL_ITERS];                   // 16 independent loads in flight
        #pragma unroll
        for (int j = 0; j < FULL_ITERS; ++j) v[j] = xr[lane + WAVE * j];
        #pragma unroll
        for (int j = 0; j < FULL_ITERS; ++j) {
            const int p = base + 4 * (lane + WAVE * j);
            if (v[j].x > 0.5f) found = p + 0;   // cndmask chains, branchless
            if (v[j].y > 0.5f) found = p + 1;
            if (v[j].z > 0.5f) found = p + 2;
            if (v[j].w > 0.5f) found = p + 3;
        }
    } else {                                 // tail segment: 832 chunks = 13/lane
        v4f v[TAIL_ITERS];
        #pragma unroll
        for (int j = 0; j < TAIL_ITERS; ++j) v[j] = xr[lane + WAVE * j];
        #pragma unroll
        for (int j = 0; j < TAIL_ITERS; ++j) {
            const int p = base + 4 * (lane + WAVE * j);
            if (v[j].x > 0.5f) found = p + 0;
            if (v[j].y > 0.5f) found = p + 1;
            if (v[j].z > 0.5f) found = p + 2;
            if (v[j].w > 0.5f) found = p + 3;
        }
    }

    const unsigned long long m = __ballot(found >= 0);
    if (!m) return;                          // 1.0 not in this segment

    // Winner: publish the skip flag (device scope), then gather + quant + store.
    if (lane == 0) atomicExch(done + t, 1);
    const int idx = __shfl(found, (int)__ffsll((long long)m) - 1);

    v4f* orow = reinterpret_cast<v4f*>(out + (size_t)t * DIM);
    if (idx == 0) {                          // PAD token -> zero row
        v4f z = 0.f;
        #pragma unroll
        for (int j = 0; j < 4; ++j) orow[lane + WAVE * j] = z;
        return;
    }

    const float  a   = alpha[0];
    const size_t col = (size_t)idx;
    float wv[16];
    #pragma unroll
    for (int j = 0; j < 4; ++j) {            // 16 independent gathers in flight
        const int d0 = 4 * lane + 256 * j;
        wv[4*j+0] = w[(size_t)(d0 + 0) * VOCAB + col];
        wv[4*j+1] = w[(size_t)(d0 + 1) * VOCAB + col];
        wv[4*j+2] = w[(size_t)(d0 + 2) * VOCAB + col];
        wv[4*j+3] = w[(size_t)(d0 + 3) * VOCAB + col];
    }
    #pragma unroll
    for (int j = 0; j < 4; ++j) {
        v4f q;
        q.x = rintf(fminf(fmaxf(wv[4*j+0] / a, -8.f), 7.f)) * a;
        q.y = rintf(fminf(fmaxf(wv[4*j+1] / a, -8.f), 7.f)) * a;
        q.z = rintf(fminf(fmaxf(wv[4*j+2] / a, -8.f), 7.f)) * a;
        q.w = rintf(fminf(fmaxf(wv[4*j+3] / a, -8.f), 7.f)) * a;
        orow[lane + WAVE * j] = q;           // lanes consecutive: 1 KB/store instr
    }
}

extern "C" void kernel_launch(void* const* d_in, const int* in_sizes, int n_in,
                              void* d_out, int out_size, void* d_ws, size_t ws_size,
                              hipStream_t stream) {
    const float* x     = (const float*)d_in[0];   // [TOKENS, VOCAB]
    const float* w     = (const float*)d_in[1];   // [DIM, VOCAB]
    const float* alpha = (const float*)d_in[2];   // [1]
    float* out         = (float*)d_out;           // [TOKENS, DIM]
    int*   done        = (int*)d_ws;              // [TOKENS] skip flags

    hipMemsetAsync(done, 0, TOKENS * sizeof(int), stream);
    emb_lsq_seg<<<TOKENS * NSEG, WAVE, 0, stream>>>(x, w, alpha, out, done);
}